// Round 17
// baseline (169.044 us; speedup 1.0000x reference)
//
#include <hip/hip_runtime.h>
#include <hip/hip_fp16.h>
#include <math.h>

typedef float    f32x4 __attribute__((ext_vector_type(4)));
typedef _Float16 f16x8 __attribute__((ext_vector_type(8)));
typedef unsigned short u16x4 __attribute__((ext_vector_type(4)));

#define NPTS 4096
#define DIM  512
#define NTB  64
#define NTILES (NTB*(NTB+1)/2)       // 2080 upper-tri tiles

// ws layout (doubles), then fp16 split arrays at 256 KiB
#define WS_U_A   0
#define WS_U_B   4096
#define WS_PAB   8192
#define WS_PAA   (8192 + NTILES)
#define WS_PBB   (8192 + 2*NTILES)
#define WS_SQA   (8192 + 3*NTILES)
#define WS_SQB   (WS_SQA + NPTS)
#define WS_F16_BYTE_OFF 262144ull
#define HELEMS ((size_t)NPTS * DIM)   // 2M f16 per split array (4 MB)

// ---- supertile tile mapping (r15-validated): 8x8-tile supertiles, diag supers
// first, then strict-upper supers; 8 contiguous 260-tile ranges via XCD swizzle.
__device__ __forceinline__ void map_tile(int raw, int& bi, int& bj) {
  const int g = (raw & 7) * 260 + (raw >> 3);
  if (g < 288) {
    const int s = g / 36, r = g % 36;
    int rj = (int)((sqrtf(8.f * r + 1.f) - 1.f) * 0.5f);
    while ((rj + 1) * (rj + 2) / 2 <= r) ++rj;
    while (rj * (rj + 1) / 2 > r) --rj;
    const int ri = r - rj * (rj + 1) / 2;
    bi = s * 8 + ri; bj = s * 8 + rj;
  } else {
    const int e = g - 288;
    const int s = e / 64, r = e % 64;
    int SBJ = 1;
    while (SBJ * (SBJ + 1) / 2 <= s) ++SBJ;
    const int SBI = s - SBJ * (SBJ - 1) / 2;
    bi = SBI * 8 + (r >> 3); bj = SBJ * 8 + (r & 7);
  }
}

// ---------------- split+sq kernel (unchanged from r14-r16) ----------------
__global__ __launch_bounds__(256) void split_kernel(
    const float* __restrict__ fa, const float* __restrict__ fb,
    _Float16* __restrict__ ha0, _Float16* __restrict__ ha1,
    _Float16* __restrict__ hb0, _Float16* __restrict__ hb1,
    double* __restrict__ ws)
{
  const int wave = threadIdx.x >> 6, lane = threadIdx.x & 63;
  const int row = blockIdx.x * 4 + wave;
  const float* src = blockIdx.y ? fb : fa;
  _Float16* o0 = blockIdx.y ? hb0 : ha0;
  _Float16* o1 = blockIdx.y ? hb1 : ha1;
  double*  dst = blockIdx.y ? (ws + WS_SQB) : (ws + WS_SQA);

  // sq: exact replica of the original sq_kernel (order-frozen)
  {
    const f32x4* p = (const f32x4*)(src + (size_t)row * DIM);
    double s = 0.0;
#pragma unroll
    for (int c = 0; c < DIM / 4 / 64; ++c) {
      f32x4 v = p[lane + c * 64];
      s += (double)v[0]*v[0] + (double)v[1]*v[1] + (double)v[2]*v[2] + (double)v[3]*v[3];
    }
    for (int off = 32; off; off >>= 1) s += __shfl_down(s, off);
    if (lane == 0) dst[row] = s;
  }

  const int band = row >> 6, sub = (row >> 4) & 3, r16 = row & 15;
  const int c = lane >> 2, g = lane & 3;

  const f32x4* p = (const f32x4*)(src + (size_t)row * DIM + lane * 8);
  f32x4 v0 = p[0], v1 = p[1];

  f16x8 h0, h1;
#pragma unroll
  for (int u = 0; u < 4; ++u) {
    float x = v0[u];
    _Float16 h = (_Float16)x;                          // RNE
    h0[u] = h;
    h1[u] = (_Float16)((x - (float)h) * 2048.0f);      // scaled residual
    float y = v1[u];
    _Float16 hh = (_Float16)y;
    h0[u + 4] = hh;
    h1[u + 4] = (_Float16)((y - (float)hh) * 2048.0f);
  }
  const size_t base = ((size_t)(band * 16 + c) * 4 + sub) * 512 + (size_t)r16 * 32;
  const int gp = (g ^ ((r16 >> 1) & 3)) * 8;
  *(f16x8*)(o0 + base + gp) = h0;
  *(f16x8*)(o1 + base + gp) = h1;
}

// ---------------- MFMA gram, direct-global frags + register double-buffer ----------
// 256 threads = 4 waves: mat = wave>>1 (0:A,1:B), h = wave&1 (row-half).
// Wave computes rows h*32..h*32+31 x all 64 cols = 2x4 MFMA 16x16 C-tiles.
// Register ping-pong: chunk c+1's 12 frags load while chunk c's 24 MFMAs run
// (pure scheduling; chunk order 0..15 ascending and per-(i,j) MFMA sequence
// {A0B0->M, A0B1->C, A1B0->C} identical to r16 -> accM/accC bit-identical).
// G = accM + accC/2048; d2 = si+sj-2G (f64); d = fp16_rne((float)sqrt(d2));
// diag forced 0.
__global__ void __launch_bounds__(256, 3)
gram_kernel(const _Float16* __restrict__ HA0, const _Float16* __restrict__ HA1,
            const _Float16* __restrict__ HB0, const _Float16* __restrict__ HB1,
            double* __restrict__ ws)
{
  int bi, bj; map_tile(blockIdx.x, bi, bj);
  const int i0 = bi * 64, j0 = bj * 64;
  const bool diag = (bi == bj);

  __shared__ unsigned short db[2][64][32];   // B-waves publish fp16 bits (8 KB)
  __shared__ double wred[4][2];

  const int t = threadIdx.x, wave = t >> 6, lane = t & 63;
  const int mat = wave >> 1, h = wave & 1;
  const int cq = lane & 15, rq = lane >> 4;

  const _Float16* S0 = mat ? HB0 : HA0;
  const _Float16* S1 = mat ? HB1 : HA1;

  const int laneoff = cq * 32 + ((rq ^ ((cq >> 1) & 3)) << 3);

  const _Float16* pA0 = S0 + ((size_t)(bi * 16) * 4 + h * 2) * 512 + laneoff;
  const _Float16* pA1 = S1 + ((size_t)(bi * 16) * 4 + h * 2) * 512 + laneoff;
  const _Float16* pB0 = S0 + ((size_t)(bj * 16) * 4) * 512 + laneoff;
  const _Float16* pB1 = S1 + ((size_t)(bj * 16) * 4) * 512 + laneoff;

  f32x4 accM[2][4], accC[2][4];
#pragma unroll
  for (int a = 0; a < 2; ++a)
#pragma unroll
    for (int b = 0; b < 4; ++b) { accM[a][b] = (f32x4){0,0,0,0}; accC[a][b] = (f32x4){0,0,0,0}; }

#define LOADC(A0v, A1v, B0v, B1v, cc) {                                   \
    const size_t o_ = (size_t)(cc) * 2048;                                \
    _Pragma("unroll")                                                     \
    for (int ti = 0; ti < 2; ++ti) {                                      \
      A0v[ti] = *(const f16x8*)(pA0 + o_ + ti * 512);                     \
      A1v[ti] = *(const f16x8*)(pA1 + o_ + ti * 512);                     \
    }                                                                     \
    _Pragma("unroll")                                                     \
    for (int tj = 0; tj < 4; ++tj) {                                      \
      B0v[tj] = *(const f16x8*)(pB0 + o_ + tj * 512);                     \
      B1v[tj] = *(const f16x8*)(pB1 + o_ + tj * 512);                     \
    } }

#define MFMAS(A0v, A1v, B0v, B1v) {                                                              \
    _Pragma("unroll")                                                                            \
    for (int tj = 0; tj < 4; ++tj)                                                               \
      _Pragma("unroll")                                                                          \
      for (int ti = 0; ti < 2; ++ti) {                                                           \
        accM[ti][tj] = __builtin_amdgcn_mfma_f32_16x16x32_f16(A0v[ti], B0v[tj], accM[ti][tj], 0, 0, 0); \
        accC[ti][tj] = __builtin_amdgcn_mfma_f32_16x16x32_f16(A0v[ti], B1v[tj], accC[ti][tj], 0, 0, 0); \
        accC[ti][tj] = __builtin_amdgcn_mfma_f32_16x16x32_f16(A1v[ti], B0v[tj], accC[ti][tj], 0, 0, 0); \
      } }

  f16x8 cA0[2], cA1[2], cB0[4], cB1[4];   // current chunk frags
  f16x8 nA0[2], nA1[2], nB0[4], nB1[4];   // next chunk frags

  LOADC(cA0, cA1, cB0, cB1, 0)
#pragma unroll 1
  for (int c = 0; c < 16; c += 2) {
    LOADC(nA0, nA1, nB0, nB1, c + 1)      // prefetch odd chunk
    MFMAS(cA0, cA1, cB0, cB1)             // compute even chunk
    if (c + 2 < 16) LOADC(cA0, cA1, cB0, cB1, c + 2)   // prefetch next even
    MFMAS(nA0, nA1, nB0, nB1)             // compute odd chunk
  }

  // NOTE: per-(i,j) chunk order is 0,1,2,...,15 ascending (identical to r16).

  // ---- epilogue: fp16 distances + stats. C/D layout (m89): col=cq, row=rq*4+r.
  const double* sqx = ws + (mat ? WS_SQB : WS_SQA);
  double*       uxp = ws + (mat ? WS_U_B : WS_U_A);

  double si[8], sj[4];
#pragma unroll
  for (int ti = 0; ti < 2; ++ti)
#pragma unroll
    for (int r = 0; r < 4; ++r)
      si[ti * 4 + r] = sqx[i0 + h * 32 + ti * 16 + rq * 4 + r];
#pragma unroll
  for (int tj = 0; tj < 4; ++tj) sj[tj] = sqx[j0 + tj * 16 + cq];

  double rs[8] = {0,0,0,0,0,0,0,0}, cs[4] = {0,0,0,0}, self = 0.0;
  unsigned short pk[2][4][4];

#pragma unroll
  for (int ti = 0; ti < 2; ++ti)
#pragma unroll
    for (int tj = 0; tj < 4; ++tj)
#pragma unroll
      for (int r = 0; r < 4; ++r) {
        double G = (double)accM[ti][tj][r] + (double)accC[ti][tj][r] * (1.0 / 2048.0);
        double d2 = si[ti * 4 + r] + sj[tj] - 2.0 * G;
        unsigned short bits = 0;
        double dq = 0.0;
        if (d2 > 0.0) {
          float df = (float)sqrt(d2);
          __half hh = __float2half(df);          // RNE -- frozen quantization
          bits = __half_as_ushort(hh);
          dq = (double)__half2float(hh);
        }
        if (diag && (h * 32 + ti * 16 + rq * 4 + r == tj * 16 + cq)) { bits = 0; dq = 0.0; }
        pk[ti][tj][r] = bits;
        rs[ti * 4 + r] += dq;
        cs[tj] += dq;
        self += dq * dq;
      }

  if (mat == 1) {
#pragma unroll
    for (int ti = 0; ti < 2; ++ti)
#pragma unroll
      for (int tj = 0; tj < 4; ++tj) {
        u16x4 v = {pk[ti][tj][0], pk[ti][tj][1], pk[ti][tj][2], pk[ti][tj][3]};
        *(u16x4*)(&db[h][lane][(ti * 4 + tj) * 4]) = v;
      }
  }

  // row sums -> u[i0 + h*32 + ti*16 + rq*4 + r]: reduce over cq (xor 1,2,4,8)
#pragma unroll
  for (int z = 0; z < 8; ++z) {
    double v = rs[z];
    v += __shfl_xor(v, 1); v += __shfl_xor(v, 2); v += __shfl_xor(v, 4); v += __shfl_xor(v, 8);
    if (cq == 0) atomicAdd(&uxp[i0 + h * 32 + (z >> 2) * 16 + rq * 4 + (z & 3)], v);
  }
  if (!diag) {  // col sums -> u[j0 + tj*16 + cq]: reduce over rq (xor 16,32); 2 halves add
#pragma unroll
    for (int tj = 0; tj < 4; ++tj) {
      double v = cs[tj];
      v += __shfl_xor(v, 16); v += __shfl_xor(v, 32);
      if (lane < 16) atomicAdd(&uxp[j0 + tj * 16 + cq], v);
    }
  }

  __syncthreads();   // db fully written

  double pab = 0.0;
  if (mat == 0) {
#pragma unroll
    for (int ti = 0; ti < 2; ++ti)
#pragma unroll
      for (int tj = 0; tj < 4; ++tj) {
        u16x4 vb = *(const u16x4*)(&db[h][lane][(ti * 4 + tj) * 4]);
#pragma unroll
        for (int r = 0; r < 4; ++r)
          pab += (double)__half2float(__ushort_as_half(pk[ti][tj][r]))
               * (double)__half2float(__ushort_as_half(vb[r]));
      }
  }

  for (int off = 32; off; off >>= 1) {
    pab  += __shfl_down(pab, off);
    self += __shfl_down(self, off);
  }
  if (lane == 0) {
    wred[wave][0] = (mat == 0) ? pab  : self;   // waves 0,1: pab halves; 2,3: pbb halves
    wred[wave][1] = (mat == 0) ? self : 0.0;    // waves 0,1: paa halves
  }
  __syncthreads();
  if (t == 0) {
    double w = diag ? 1.0 : 2.0;
    ws[WS_PAB + blockIdx.x] = w * (wred[0][0] + wred[1][0]);
    ws[WS_PAA + blockIdx.x] = w * (wred[0][1] + wred[1][1]);
    ws[WS_PBB + blockIdx.x] = w * (wred[2][0] + wred[3][0]);
  }
}

// ---------------- final: reduce stats, closed-form U-centered dots --------------------
__global__ __launch_bounds__(256) void final_kernel(const double* __restrict__ ws,
                                                    float* __restrict__ out)
{
  const int t = threadIdx.x;
  double sa = 0, sb = 0, uab = 0, uaa = 0, ubb = 0, ab = 0, aa = 0, bb = 0;
  for (int i = t; i < NPTS; i += 256) {
    double a = ws[WS_U_A + i], b = ws[WS_U_B + i];
    sa += a; sb += b; uab += a * b; uaa += a * a; ubb += b * b;
  }
  for (int i = t; i < NTILES; i += 256) {
    ab += ws[WS_PAB + i]; aa += ws[WS_PAA + i]; bb += ws[WS_PBB + i];
  }
  for (int off = 32; off; off >>= 1) {
    sa  += __shfl_down(sa, off);  sb  += __shfl_down(sb, off);
    uab += __shfl_down(uab, off); uaa += __shfl_down(uaa, off); ubb += __shfl_down(ubb, off);
    ab  += __shfl_down(ab, off);  aa  += __shfl_down(aa, off);  bb  += __shfl_down(bb, off);
  }
  __shared__ double red[4][8];
  int wave = t >> 6, lane = t & 63;
  if (lane == 0) {
    red[wave][0] = sa;  red[wave][1] = sb;  red[wave][2] = uab; red[wave][3] = uaa;
    red[wave][4] = ubb; red[wave][5] = ab;  red[wave][6] = aa;  red[wave][7] = bb;
  }
  __syncthreads();
  if (t == 0) {
    double v[8] = {0,0,0,0,0,0,0,0};
    for (int qq = 0; qq < 4; ++qq) for (int z = 0; z < 8; ++z) v[z] += red[qq][z];
    const double SA = v[0], SB = v[1], UAB = v[2], UAA = v[3], UBB = v[4];
    const double PAB = v[5], PAA = v[6], PBB = v[7];
    const double n = (double)NPTS, nm2 = n - 2.0;
    auto dotv = [&](double P, double U, double sx, double sy) {
      double tX = sx / ((n - 1.0) * nm2), tY = sy / ((n - 1.0) * nm2);
      double RX = sx / nm2, RY = sy / nm2;
      double su  = U / nm2;
      double srr = U / (nm2 * nm2);
      double full = P - 4.0 * su + tY * sx + tX * sy + 2.0 * n * srr + 2.0 * RX * RY
                  - 2.0 * n * tY * RX - 2.0 * n * tX * RY + n * n * tX * tY;
      double dg = n * tX * tY - 2.0 * tX * RY - 2.0 * tY * RX + 4.0 * srr;
      return full - dg;
    };
    const double denomc = n * (n - 3.0);
    double dab = dotv(PAB, UAB, SA, SB) / denomc;
    double daa = dotv(PAA, UAA, SA, SA) / denomc;
    double dbb = dotv(PBB, UBB, SB, SB) / denomc;
    double dn = sqrt(daa * dbb);
    if (dn < 1e-9) dn = 1e-9;
    out[0] = (float)(dab / dn);
  }
}

extern "C" void kernel_launch(void* const* d_in, const int* in_sizes, int n_in,
                              void* d_out, int out_size, void* d_ws, size_t ws_size,
                              hipStream_t stream) {
  const float* fa = (const float*)d_in[0];
  const float* fb = (const float*)d_in[1];
  double* ws = (double*)d_ws;

  _Float16* HA0 = (_Float16*)((char*)d_ws + WS_F16_BYTE_OFF);
  _Float16* HA1 = HA0 + HELEMS;
  _Float16* HB0 = HA1 + HELEMS;
  _Float16* HB1 = HB0 + HELEMS;

  // only the u accumulators need zeroing (P slots + sq are plain stores)
  hipMemsetAsync(d_ws, 0, 8192 * sizeof(double), stream);
  split_kernel<<<dim3(NPTS / 4, 2), 256, 0, stream>>>(fa, fb, HA0, HA1, HB0, HB1, ws);
  gram_kernel<<<NTILES, 256, 0, stream>>>(HA0, HA1, HB0, HB1, ws);
  final_kernel<<<1, 256, 0, stream>>>(ws, (float*)d_out);
}

// Round 18
// 120.206 us; speedup vs baseline: 1.4063x; 1.4063x over previous
//
#include <hip/hip_runtime.h>
#include <hip/hip_fp16.h>
#include <math.h>

typedef float    f32x4 __attribute__((ext_vector_type(4)));
typedef _Float16 f16x8 __attribute__((ext_vector_type(8)));
typedef unsigned short u16x4 __attribute__((ext_vector_type(4)));

#define NPTS 4096
#define DIM  512
#define NTB  64
#define NTILES (NTB*(NTB+1)/2)       // 2080 upper-tri tiles

// ws layout (doubles), then fp16 split arrays at 256 KiB
#define WS_U_A   0
#define WS_U_B   4096
#define WS_PAB   8192
#define WS_PAA   (8192 + NTILES)
#define WS_PBB   (8192 + 2*NTILES)
#define WS_SQA   (8192 + 3*NTILES)
#define WS_SQB   (WS_SQA + NPTS)
#define WS_F16_BYTE_OFF 262144ull
#define HELEMS ((size_t)NPTS * DIM)   // 2M f16 per split array (4 MB)

// ---- supertile tile mapping (r15-validated): 8x8-tile supertiles, diag supers
// first, then strict-upper supers; 8 contiguous 260-tile ranges via XCD swizzle.
__device__ __forceinline__ void map_tile(int raw, int& bi, int& bj) {
  const int g = (raw & 7) * 260 + (raw >> 3);
  if (g < 288) {
    const int s = g / 36, r = g % 36;
    int rj = (int)((sqrtf(8.f * r + 1.f) - 1.f) * 0.5f);
    while ((rj + 1) * (rj + 2) / 2 <= r) ++rj;
    while (rj * (rj + 1) / 2 > r) --rj;
    const int ri = r - rj * (rj + 1) / 2;
    bi = s * 8 + ri; bj = s * 8 + rj;
  } else {
    const int e = g - 288;
    const int s = e / 64, r = e % 64;
    int SBJ = 1;
    while (SBJ * (SBJ + 1) / 2 <= s) ++SBJ;
    const int SBI = s - SBJ * (SBJ - 1) / 2;
    bi = SBI * 8 + (r >> 3); bj = SBJ * 8 + (r & 7);
  }
}

// ---------------- split+sq kernel (unchanged from r14-r17) ----------------
__global__ __launch_bounds__(256) void split_kernel(
    const float* __restrict__ fa, const float* __restrict__ fb,
    _Float16* __restrict__ ha0, _Float16* __restrict__ ha1,
    _Float16* __restrict__ hb0, _Float16* __restrict__ hb1,
    double* __restrict__ ws)
{
  const int wave = threadIdx.x >> 6, lane = threadIdx.x & 63;
  const int row = blockIdx.x * 4 + wave;
  const float* src = blockIdx.y ? fb : fa;
  _Float16* o0 = blockIdx.y ? hb0 : ha0;
  _Float16* o1 = blockIdx.y ? hb1 : ha1;
  double*  dst = blockIdx.y ? (ws + WS_SQB) : (ws + WS_SQA);

  // sq: exact replica of the original sq_kernel (order-frozen)
  {
    const f32x4* p = (const f32x4*)(src + (size_t)row * DIM);
    double s = 0.0;
#pragma unroll
    for (int c = 0; c < DIM / 4 / 64; ++c) {
      f32x4 v = p[lane + c * 64];
      s += (double)v[0]*v[0] + (double)v[1]*v[1] + (double)v[2]*v[2] + (double)v[3]*v[3];
    }
    for (int off = 32; off; off >>= 1) s += __shfl_down(s, off);
    if (lane == 0) dst[row] = s;
  }

  const int band = row >> 6, sub = (row >> 4) & 3, r16 = row & 15;
  const int c = lane >> 2, g = lane & 3;

  const f32x4* p = (const f32x4*)(src + (size_t)row * DIM + lane * 8);
  f32x4 v0 = p[0], v1 = p[1];

  f16x8 h0, h1;
#pragma unroll
  for (int u = 0; u < 4; ++u) {
    float x = v0[u];
    _Float16 h = (_Float16)x;                          // RNE
    h0[u] = h;
    h1[u] = (_Float16)((x - (float)h) * 2048.0f);      // scaled residual
    float y = v1[u];
    _Float16 hh = (_Float16)y;
    h0[u + 4] = hh;
    h1[u + 4] = (_Float16)((y - (float)hh) * 2048.0f);
  }
  const size_t base = ((size_t)(band * 16 + c) * 4 + sub) * 512 + (size_t)r16 * 32;
  const int gp = (g ^ ((r16 >> 1) & 3)) * 8;
  *(f16x8*)(o0 + base + gp) = h0;
  *(f16x8*)(o1 + base + gp) = h1;
}

// ---------------- MFMA gram, direct-global frags + register double-buffer ----------
// 256 threads = 4 waves: mat = wave>>1 (0:A,1:B), h = wave&1 (row-half).
// Wave computes rows h*32..h*32+31 x all 64 cols = 2x4 MFMA 16x16 C-tiles.
// Register ping-pong: chunk c+1's 12 frags load while chunk c's 24 MFMAs run.
// __launch_bounds__(256, 2): 256-reg unified budget so BOTH frag buffers
// (2 x 48) + 64 acc fit in registers (r17's (256,3)=170 budget spilled -> 188MB
// scratch; this is the corrected-budget rerun of the same schedule).
// NUMERICS FROZEN: chunk order 0..15 ascending, per-(i,j) MFMA sequence
// {A0B0->M, A0B1->C, A1B0->C} identical to r16/r17 -> accM/accC bit-identical.
// G = accM + accC/2048; d2 = si+sj-2G (f64); d = fp16_rne((float)sqrt(d2));
// diag forced 0.
__global__ void __launch_bounds__(256, 2)
gram_kernel(const _Float16* __restrict__ HA0, const _Float16* __restrict__ HA1,
            const _Float16* __restrict__ HB0, const _Float16* __restrict__ HB1,
            double* __restrict__ ws)
{
  int bi, bj; map_tile(blockIdx.x, bi, bj);
  const int i0 = bi * 64, j0 = bj * 64;
  const bool diag = (bi == bj);

  __shared__ unsigned short db[2][64][32];   // B-waves publish fp16 bits (8 KB)
  __shared__ double wred[4][2];

  const int t = threadIdx.x, wave = t >> 6, lane = t & 63;
  const int mat = wave >> 1, h = wave & 1;
  const int cq = lane & 15, rq = lane >> 4;

  const _Float16* S0 = mat ? HB0 : HA0;
  const _Float16* S1 = mat ? HB1 : HA1;

  const int laneoff = cq * 32 + ((rq ^ ((cq >> 1) & 3)) << 3);

  const _Float16* pA0 = S0 + ((size_t)(bi * 16) * 4 + h * 2) * 512 + laneoff;
  const _Float16* pA1 = S1 + ((size_t)(bi * 16) * 4 + h * 2) * 512 + laneoff;
  const _Float16* pB0 = S0 + ((size_t)(bj * 16) * 4) * 512 + laneoff;
  const _Float16* pB1 = S1 + ((size_t)(bj * 16) * 4) * 512 + laneoff;

  f32x4 accM[2][4], accC[2][4];
#pragma unroll
  for (int a = 0; a < 2; ++a)
#pragma unroll
    for (int b = 0; b < 4; ++b) { accM[a][b] = (f32x4){0,0,0,0}; accC[a][b] = (f32x4){0,0,0,0}; }

#define LOADC(A0v, A1v, B0v, B1v, cc) {                                   \
    const size_t o_ = (size_t)(cc) * 2048;                                \
    _Pragma("unroll")                                                     \
    for (int ti = 0; ti < 2; ++ti) {                                      \
      A0v[ti] = *(const f16x8*)(pA0 + o_ + ti * 512);                     \
      A1v[ti] = *(const f16x8*)(pA1 + o_ + ti * 512);                     \
    }                                                                     \
    _Pragma("unroll")                                                     \
    for (int tj = 0; tj < 4; ++tj) {                                      \
      B0v[tj] = *(const f16x8*)(pB0 + o_ + tj * 512);                     \
      B1v[tj] = *(const f16x8*)(pB1 + o_ + tj * 512);                     \
    } }

#define MFMAS(A0v, A1v, B0v, B1v) {                                                              \
    _Pragma("unroll")                                                                            \
    for (int tj = 0; tj < 4; ++tj)                                                               \
      _Pragma("unroll")                                                                          \
      for (int ti = 0; ti < 2; ++ti) {                                                           \
        accM[ti][tj] = __builtin_amdgcn_mfma_f32_16x16x32_f16(A0v[ti], B0v[tj], accM[ti][tj], 0, 0, 0); \
        accC[ti][tj] = __builtin_amdgcn_mfma_f32_16x16x32_f16(A0v[ti], B1v[tj], accC[ti][tj], 0, 0, 0); \
        accC[ti][tj] = __builtin_amdgcn_mfma_f32_16x16x32_f16(A1v[ti], B0v[tj], accC[ti][tj], 0, 0, 0); \
      } }

  f16x8 cA0[2], cA1[2], cB0[4], cB1[4];   // current chunk frags
  f16x8 nA0[2], nA1[2], nB0[4], nB1[4];   // next chunk frags

  LOADC(cA0, cA1, cB0, cB1, 0)
#pragma unroll 1
  for (int c = 0; c < 16; c += 2) {
    LOADC(nA0, nA1, nB0, nB1, c + 1)      // prefetch odd chunk
    MFMAS(cA0, cA1, cB0, cB1)             // compute even chunk
    if (c + 2 < 16) LOADC(cA0, cA1, cB0, cB1, c + 2)   // prefetch next even
    MFMAS(nA0, nA1, nB0, nB1)             // compute odd chunk
  }

  // ---- epilogue: fp16 distances + stats. C/D layout (m89): col=cq, row=rq*4+r.
  const double* sqx = ws + (mat ? WS_SQB : WS_SQA);
  double*       uxp = ws + (mat ? WS_U_B : WS_U_A);

  double si[8], sj[4];
#pragma unroll
  for (int ti = 0; ti < 2; ++ti)
#pragma unroll
    for (int r = 0; r < 4; ++r)
      si[ti * 4 + r] = sqx[i0 + h * 32 + ti * 16 + rq * 4 + r];
#pragma unroll
  for (int tj = 0; tj < 4; ++tj) sj[tj] = sqx[j0 + tj * 16 + cq];

  double rs[8] = {0,0,0,0,0,0,0,0}, cs[4] = {0,0,0,0}, self = 0.0;
  unsigned short pk[2][4][4];

#pragma unroll
  for (int ti = 0; ti < 2; ++ti)
#pragma unroll
    for (int tj = 0; tj < 4; ++tj)
#pragma unroll
      for (int r = 0; r < 4; ++r) {
        double G = (double)accM[ti][tj][r] + (double)accC[ti][tj][r] * (1.0 / 2048.0);
        double d2 = si[ti * 4 + r] + sj[tj] - 2.0 * G;
        unsigned short bits = 0;
        double dq = 0.0;
        if (d2 > 0.0) {
          float df = (float)sqrt(d2);
          __half hh = __float2half(df);          // RNE -- frozen quantization
          bits = __half_as_ushort(hh);
          dq = (double)__half2float(hh);
        }
        if (diag && (h * 32 + ti * 16 + rq * 4 + r == tj * 16 + cq)) { bits = 0; dq = 0.0; }
        pk[ti][tj][r] = bits;
        rs[ti * 4 + r] += dq;
        cs[tj] += dq;
        self += dq * dq;
      }

  if (mat == 1) {
#pragma unroll
    for (int ti = 0; ti < 2; ++ti)
#pragma unroll
      for (int tj = 0; tj < 4; ++tj) {
        u16x4 v = {pk[ti][tj][0], pk[ti][tj][1], pk[ti][tj][2], pk[ti][tj][3]};
        *(u16x4*)(&db[h][lane][(ti * 4 + tj) * 4]) = v;
      }
  }

  // row sums -> u[i0 + h*32 + ti*16 + rq*4 + r]: reduce over cq (xor 1,2,4,8)
#pragma unroll
  for (int z = 0; z < 8; ++z) {
    double v = rs[z];
    v += __shfl_xor(v, 1); v += __shfl_xor(v, 2); v += __shfl_xor(v, 4); v += __shfl_xor(v, 8);
    if (cq == 0) atomicAdd(&uxp[i0 + h * 32 + (z >> 2) * 16 + rq * 4 + (z & 3)], v);
  }
  if (!diag) {  // col sums -> u[j0 + tj*16 + cq]: reduce over rq (xor 16,32); 2 halves add
#pragma unroll
    for (int tj = 0; tj < 4; ++tj) {
      double v = cs[tj];
      v += __shfl_xor(v, 16); v += __shfl_xor(v, 32);
      if (lane < 16) atomicAdd(&uxp[j0 + tj * 16 + cq], v);
    }
  }

  __syncthreads();   // db fully written

  double pab = 0.0;
  if (mat == 0) {
#pragma unroll
    for (int ti = 0; ti < 2; ++ti)
#pragma unroll
      for (int tj = 0; tj < 4; ++tj) {
        u16x4 vb = *(const u16x4*)(&db[h][lane][(ti * 4 + tj) * 4]);
#pragma unroll
        for (int r = 0; r < 4; ++r)
          pab += (double)__half2float(__ushort_as_half(pk[ti][tj][r]))
               * (double)__half2float(__ushort_as_half(vb[r]));
      }
  }

  for (int off = 32; off; off >>= 1) {
    pab  += __shfl_down(pab, off);
    self += __shfl_down(self, off);
  }
  if (lane == 0) {
    wred[wave][0] = (mat == 0) ? pab  : self;   // waves 0,1: pab halves; 2,3: pbb halves
    wred[wave][1] = (mat == 0) ? self : 0.0;    // waves 0,1: paa halves
  }
  __syncthreads();
  if (t == 0) {
    double w = diag ? 1.0 : 2.0;
    ws[WS_PAB + blockIdx.x] = w * (wred[0][0] + wred[1][0]);
    ws[WS_PAA + blockIdx.x] = w * (wred[0][1] + wred[1][1]);
    ws[WS_PBB + blockIdx.x] = w * (wred[2][0] + wred[3][0]);
  }
}

// ---------------- final: reduce stats, closed-form U-centered dots --------------------
__global__ __launch_bounds__(256) void final_kernel(const double* __restrict__ ws,
                                                    float* __restrict__ out)
{
  const int t = threadIdx.x;
  double sa = 0, sb = 0, uab = 0, uaa = 0, ubb = 0, ab = 0, aa = 0, bb = 0;
  for (int i = t; i < NPTS; i += 256) {
    double a = ws[WS_U_A + i], b = ws[WS_U_B + i];
    sa += a; sb += b; uab += a * b; uaa += a * a; ubb += b * b;
  }
  for (int i = t; i < NTILES; i += 256) {
    ab += ws[WS_PAB + i]; aa += ws[WS_PAA + i]; bb += ws[WS_PBB + i];
  }
  for (int off = 32; off; off >>= 1) {
    sa  += __shfl_down(sa, off);  sb  += __shfl_down(sb, off);
    uab += __shfl_down(uab, off); uaa += __shfl_down(uaa, off); ubb += __shfl_down(ubb, off);
    ab  += __shfl_down(ab, off);  aa  += __shfl_down(aa, off);  bb  += __shfl_down(bb, off);
  }
  __shared__ double red[4][8];
  int wave = t >> 6, lane = t & 63;
  if (lane == 0) {
    red[wave][0] = sa;  red[wave][1] = sb;  red[wave][2] = uab; red[wave][3] = uaa;
    red[wave][4] = ubb; red[wave][5] = ab;  red[wave][6] = aa;  red[wave][7] = bb;
  }
  __syncthreads();
  if (t == 0) {
    double v[8] = {0,0,0,0,0,0,0,0};
    for (int qq = 0; qq < 4; ++qq) for (int z = 0; z < 8; ++z) v[z] += red[qq][z];
    const double SA = v[0], SB = v[1], UAB = v[2], UAA = v[3], UBB = v[4];
    const double PAB = v[5], PAA = v[6], PBB = v[7];
    const double n = (double)NPTS, nm2 = n - 2.0;
    auto dotv = [&](double P, double U, double sx, double sy) {
      double tX = sx / ((n - 1.0) * nm2), tY = sy / ((n - 1.0) * nm2);
      double RX = sx / nm2, RY = sy / nm2;
      double su  = U / nm2;
      double srr = U / (nm2 * nm2);
      double full = P - 4.0 * su + tY * sx + tX * sy + 2.0 * n * srr + 2.0 * RX * RY
                  - 2.0 * n * tY * RX - 2.0 * n * tX * RY + n * n * tX * tY;
      double dg = n * tX * tY - 2.0 * tX * RY - 2.0 * tY * RX + 4.0 * srr;
      return full - dg;
    };
    const double denomc = n * (n - 3.0);
    double dab = dotv(PAB, UAB, SA, SB) / denomc;
    double daa = dotv(PAA, UAA, SA, SA) / denomc;
    double dbb = dotv(PBB, UBB, SB, SB) / denomc;
    double dn = sqrt(daa * dbb);
    if (dn < 1e-9) dn = 1e-9;
    out[0] = (float)(dab / dn);
  }
}

extern "C" void kernel_launch(void* const* d_in, const int* in_sizes, int n_in,
                              void* d_out, int out_size, void* d_ws, size_t ws_size,
                              hipStream_t stream) {
  const float* fa = (const float*)d_in[0];
  const float* fb = (const float*)d_in[1];
  double* ws = (double*)d_ws;

  _Float16* HA0 = (_Float16*)((char*)d_ws + WS_F16_BYTE_OFF);
  _Float16* HA1 = HA0 + HELEMS;
  _Float16* HB0 = HA1 + HELEMS;
  _Float16* HB1 = HB0 + HELEMS;

  // only the u accumulators need zeroing (P slots + sq are plain stores)
  hipMemsetAsync(d_ws, 0, 8192 * sizeof(double), stream);
  split_kernel<<<dim3(NPTS / 4, 2), 256, 0, stream>>>(fa, fb, HA0, HA1, HB0, HB1, ws);
  gram_kernel<<<NTILES, 256, 0, stream>>>(HA0, HA1, HB0, HB1, ws);
  final_kernel<<<1, 256, 0, stream>>>(ws, (float*)d_out);
}

// Round 20
// 116.726 us; speedup vs baseline: 1.4482x; 1.0298x over previous
//
#include <hip/hip_runtime.h>
#include <hip/hip_fp16.h>
#include <math.h>

typedef float    f32x4 __attribute__((ext_vector_type(4)));
typedef _Float16 f16x8 __attribute__((ext_vector_type(8)));
typedef unsigned short u16x4 __attribute__((ext_vector_type(4)));

#define NPTS 4096
#define DIM  512
#define NTB  64
#define NTILES (NTB*(NTB+1)/2)       // 2080 upper-tri tiles

// ws layout (doubles), then fp16 split arrays at 256 KiB
#define WS_U_A   0
#define WS_U_B   4096
#define WS_PAB   8192
#define WS_PAA   (8192 + NTILES)
#define WS_PBB   (8192 + 2*NTILES)
#define WS_SQA   (8192 + 3*NTILES)
#define WS_SQB   (WS_SQA + NPTS)
#define WS_F16_BYTE_OFF 262144ull
#define HELEMS ((size_t)NPTS * DIM)   // 2M f16 per split array (4 MB)

// ---- supertile tile mapping (r15-validated) ----
__device__ __forceinline__ void map_tile(int raw, int& bi, int& bj) {
  const int g = (raw & 7) * 260 + (raw >> 3);
  if (g < 288) {
    const int s = g / 36, r = g % 36;
    int rj = (int)((sqrtf(8.f * r + 1.f) - 1.f) * 0.5f);
    while ((rj + 1) * (rj + 2) / 2 <= r) ++rj;
    while (rj * (rj + 1) / 2 > r) --rj;
    const int ri = r - rj * (rj + 1) / 2;
    bi = s * 8 + ri; bj = s * 8 + rj;
  } else {
    const int e = g - 288;
    const int s = e / 64, r = e % 64;
    int SBJ = 1;
    while (SBJ * (SBJ + 1) / 2 <= s) ++SBJ;
    const int SBI = s - SBJ * (SBJ - 1) / 2;
    bi = SBI * 8 + (r >> 3); bj = SBJ * 8 + (r & 7);
  }
}

// ---------------- split+sq kernel (byte-identical to r14-r18) ----------------
__global__ __launch_bounds__(256) void split_kernel(
    const float* __restrict__ fa, const float* __restrict__ fb,
    _Float16* __restrict__ ha0, _Float16* __restrict__ ha1,
    _Float16* __restrict__ hb0, _Float16* __restrict__ hb1,
    double* __restrict__ ws)
{
  const int wave = threadIdx.x >> 6, lane = threadIdx.x & 63;
  const int row = blockIdx.x * 4 + wave;
  const float* src = blockIdx.y ? fb : fa;
  _Float16* o0 = blockIdx.y ? hb0 : ha0;
  _Float16* o1 = blockIdx.y ? hb1 : ha1;
  double*  dst = blockIdx.y ? (ws + WS_SQB) : (ws + WS_SQA);

  // sq: exact replica of the original sq_kernel (order-frozen)
  {
    const f32x4* p = (const f32x4*)(src + (size_t)row * DIM);
    double s = 0.0;
#pragma unroll
    for (int c = 0; c < DIM / 4 / 64; ++c) {
      f32x4 v = p[lane + c * 64];
      s += (double)v[0]*v[0] + (double)v[1]*v[1] + (double)v[2]*v[2] + (double)v[3]*v[3];
    }
    for (int off = 32; off; off >>= 1) s += __shfl_down(s, off);
    if (lane == 0) dst[row] = s;
  }

  const int band = row >> 6, sub = (row >> 4) & 3, r16 = row & 15;
  const int c = lane >> 2, g = lane & 3;

  const f32x4* p = (const f32x4*)(src + (size_t)row * DIM + lane * 8);
  f32x4 v0 = p[0], v1 = p[1];

  f16x8 h0, h1;
#pragma unroll
  for (int u = 0; u < 4; ++u) {
    float x = v0[u];
    _Float16 h = (_Float16)x;                          // RNE
    h0[u] = h;
    h1[u] = (_Float16)((x - (float)h) * 2048.0f);      // scaled residual
    float y = v1[u];
    _Float16 hh = (_Float16)y;
    h0[u + 4] = hh;
    h1[u + 4] = (_Float16)((y - (float)hh) * 2048.0f);
  }
  const size_t base = ((size_t)(band * 16 + c) * 4 + sub) * 512 + (size_t)r16 * 32;
  const int gp = (g ^ ((r16 >> 1) & 3)) * 8;
  *(f16x8*)(o0 + base + gp) = h0;
  *(f16x8*)(o1 + base + gp) = h1;
}

// ---------------- MFMA gram, direct-global frags: r18 arithmetic, B-only prefetch ----------
// 256 threads = 4 waves: mat = wave>>1 (0:A,1:B), h = wave&1 (row-half).
// Wave computes rows h*32..h*32+31 x all 64 cols = 2x4 MFMA 16x16 C-tiles.
// SCHEDULE-ONLY change vs r18: ping-pong prefetch of the 8 B-frags (A-frags
// loaded just-in-time) -> register footprint ~164 fits __launch_bounds__(256,3)
// = 3 waves/SIMD WITH prefetch (r18 was 2 w/SIMD full-prefetch; r16 3 w/SIMD
// none). EVERYTHING ELSE IS BYTE-IDENTICAL TO r18: per-(i,j) chunk order 0..15
// ascending, per-chunk MFMA sequence {A0B0->M, A0B1->C, A1B0->C}, epilogue,
// ALL reduction trees / shuffle trees / atomic partitioning (r19 showed the
// output sits ~1e-8-relative from a bf16 midpoint -> reductions are frozen).
// G = accM + accC/2048; d2 = si+sj-2G (f64); d = fp16_rne((float)sqrt(d2));
// diag forced 0.
__global__ void __launch_bounds__(256, 3)
gram_kernel(const _Float16* __restrict__ HA0, const _Float16* __restrict__ HA1,
            const _Float16* __restrict__ HB0, const _Float16* __restrict__ HB1,
            double* __restrict__ ws)
{
  int bi, bj; map_tile(blockIdx.x, bi, bj);
  const int i0 = bi * 64, j0 = bj * 64;
  const bool diag = (bi == bj);

  __shared__ unsigned short db[2][64][32];   // B-waves publish fp16 bits (8 KB)
  __shared__ double wred[4][2];

  const int t = threadIdx.x, wave = t >> 6, lane = t & 63;
  const int mat = wave >> 1, h = wave & 1;
  const int cq = lane & 15, rq = lane >> 4;

  const _Float16* S0 = mat ? HB0 : HA0;
  const _Float16* S1 = mat ? HB1 : HA1;

  const int laneoff = cq * 32 + ((rq ^ ((cq >> 1) & 3)) << 3);

  const _Float16* pA0 = S0 + ((size_t)(bi * 16) * 4 + h * 2) * 512 + laneoff;
  const _Float16* pA1 = S1 + ((size_t)(bi * 16) * 4 + h * 2) * 512 + laneoff;
  const _Float16* pB0 = S0 + ((size_t)(bj * 16) * 4) * 512 + laneoff;
  const _Float16* pB1 = S1 + ((size_t)(bj * 16) * 4) * 512 + laneoff;

  f32x4 accM[2][4], accC[2][4];
#pragma unroll
  for (int a = 0; a < 2; ++a)
#pragma unroll
    for (int b = 0; b < 4; ++b) { accM[a][b] = (f32x4){0,0,0,0}; accC[a][b] = (f32x4){0,0,0,0}; }

#define LOADA(A0v, A1v, cc) {                                             \
    const size_t o_ = (size_t)(cc) * 2048;                                \
    _Pragma("unroll")                                                     \
    for (int ti = 0; ti < 2; ++ti) {                                      \
      A0v[ti] = *(const f16x8*)(pA0 + o_ + ti * 512);                     \
      A1v[ti] = *(const f16x8*)(pA1 + o_ + ti * 512);                     \
    } }

#define LOADB(B0v, B1v, cc) {                                             \
    const size_t o_ = (size_t)(cc) * 2048;                                \
    _Pragma("unroll")                                                     \
    for (int tj = 0; tj < 4; ++tj) {                                      \
      B0v[tj] = *(const f16x8*)(pB0 + o_ + tj * 512);                     \
      B1v[tj] = *(const f16x8*)(pB1 + o_ + tj * 512);                     \
    } }

#define MFMAS(A0v, A1v, B0v, B1v) {                                                              \
    _Pragma("unroll")                                                                            \
    for (int tj = 0; tj < 4; ++tj)                                                               \
      _Pragma("unroll")                                                                          \
      for (int ti = 0; ti < 2; ++ti) {                                                           \
        accM[ti][tj] = __builtin_amdgcn_mfma_f32_16x16x32_f16(A0v[ti], B0v[tj], accM[ti][tj], 0, 0, 0); \
        accC[ti][tj] = __builtin_amdgcn_mfma_f32_16x16x32_f16(A0v[ti], B1v[tj], accC[ti][tj], 0, 0, 0); \
        accC[ti][tj] = __builtin_amdgcn_mfma_f32_16x16x32_f16(A1v[ti], B0v[tj], accC[ti][tj], 0, 0, 0); \
      } }

  f16x8 aA0[2], aA1[2];                   // JIT A frags (reloaded per chunk)
  f16x8 cB0[4], cB1[4], nB0[4], nB1[4];   // B frag ping-pong

  LOADB(cB0, cB1, 0)
#pragma unroll 1
  for (int c = 0; c < 16; c += 2) {
    LOADA(aA0, aA1, c)                    // JIT A for even chunk
    LOADB(nB0, nB1, c + 1)                // prefetch odd-chunk B
    MFMAS(aA0, aA1, cB0, cB1)             // compute even chunk
    LOADA(aA0, aA1, c + 1)                // JIT A for odd chunk
    if (c + 2 < 16) LOADB(cB0, cB1, c + 2)   // prefetch next even B
    MFMAS(aA0, aA1, nB0, nB1)             // compute odd chunk
  }

  // ---- epilogue: fp16 distances + stats (byte-identical to r18) ----
  const double* sqx = ws + (mat ? WS_SQB : WS_SQA);
  double*       uxp = ws + (mat ? WS_U_B : WS_U_A);

  double si[8], sj[4];
#pragma unroll
  for (int ti = 0; ti < 2; ++ti)
#pragma unroll
    for (int r = 0; r < 4; ++r)
      si[ti * 4 + r] = sqx[i0 + h * 32 + ti * 16 + rq * 4 + r];
#pragma unroll
  for (int tj = 0; tj < 4; ++tj) sj[tj] = sqx[j0 + tj * 16 + cq];

  double rs[8] = {0,0,0,0,0,0,0,0}, cs[4] = {0,0,0,0}, self = 0.0;
  unsigned short pk[2][4][4];

#pragma unroll
  for (int ti = 0; ti < 2; ++ti)
#pragma unroll
    for (int tj = 0; tj < 4; ++tj)
#pragma unroll
      for (int r = 0; r < 4; ++r) {
        double G = (double)accM[ti][tj][r] + (double)accC[ti][tj][r] * (1.0 / 2048.0);
        double d2 = si[ti * 4 + r] + sj[tj] - 2.0 * G;
        unsigned short bits = 0;
        double dq = 0.0;
        if (d2 > 0.0) {
          float df = (float)sqrt(d2);
          __half hh = __float2half(df);          // RNE -- frozen quantization
          bits = __half_as_ushort(hh);
          dq = (double)__half2float(hh);
        }
        if (diag && (h * 32 + ti * 16 + rq * 4 + r == tj * 16 + cq)) { bits = 0; dq = 0.0; }
        pk[ti][tj][r] = bits;
        rs[ti * 4 + r] += dq;
        cs[tj] += dq;
        self += dq * dq;
      }

  if (mat == 1) {
#pragma unroll
    for (int ti = 0; ti < 2; ++ti)
#pragma unroll
      for (int tj = 0; tj < 4; ++tj) {
        u16x4 v = {pk[ti][tj][0], pk[ti][tj][1], pk[ti][tj][2], pk[ti][tj][3]};
        *(u16x4*)(&db[h][lane][(ti * 4 + tj) * 4]) = v;
      }
  }

  // row sums -> u[i0 + h*32 + ti*16 + rq*4 + r]: reduce over cq (xor 1,2,4,8)
#pragma unroll
  for (int z = 0; z < 8; ++z) {
    double v = rs[z];
    v += __shfl_xor(v, 1); v += __shfl_xor(v, 2); v += __shfl_xor(v, 4); v += __shfl_xor(v, 8);
    if (cq == 0) atomicAdd(&uxp[i0 + h * 32 + (z >> 2) * 16 + rq * 4 + (z & 3)], v);
  }
  if (!diag) {  // col sums -> u[j0 + tj*16 + cq]: reduce over rq (xor 16,32); 2 halves add
#pragma unroll
    for (int tj = 0; tj < 4; ++tj) {
      double v = cs[tj];
      v += __shfl_xor(v, 16); v += __shfl_xor(v, 32);
      if (lane < 16) atomicAdd(&uxp[j0 + tj * 16 + cq], v);
    }
  }

  __syncthreads();   // db fully written

  double pab = 0.0;
  if (mat == 0) {
#pragma unroll
    for (int ti = 0; ti < 2; ++ti)
#pragma unroll
      for (int tj = 0; tj < 4; ++tj) {
        u16x4 vb = *(const u16x4*)(&db[h][lane][(ti * 4 + tj) * 4]);
#pragma unroll
        for (int r = 0; r < 4; ++r)
          pab += (double)__half2float(__ushort_as_half(pk[ti][tj][r]))
               * (double)__half2float(__ushort_as_half(vb[r]));
      }
  }

  for (int off = 32; off; off >>= 1) {
    pab  += __shfl_down(pab, off);
    self += __shfl_down(self, off);
  }
  if (lane == 0) {
    wred[wave][0] = (mat == 0) ? pab  : self;   // waves 0,1: pab halves; 2,3: pbb halves
    wred[wave][1] = (mat == 0) ? self : 0.0;    // waves 0,1: paa halves
  }
  __syncthreads();
  if (t == 0) {
    double w = diag ? 1.0 : 2.0;
    ws[WS_PAB + blockIdx.x] = w * (wred[0][0] + wred[1][0]);
    ws[WS_PAA + blockIdx.x] = w * (wred[0][1] + wred[1][1]);
    ws[WS_PBB + blockIdx.x] = w * (wred[2][0] + wred[3][0]);
  }
}

// ---------------- final: reduce stats, closed-form U-centered dots --------------------
__global__ __launch_bounds__(256) void final_kernel(const double* __restrict__ ws,
                                                    float* __restrict__ out)
{
  const int t = threadIdx.x;
  double sa = 0, sb = 0, uab = 0, uaa = 0, ubb = 0, ab = 0, aa = 0, bb = 0;
  for (int i = t; i < NPTS; i += 256) {
    double a = ws[WS_U_A + i], b = ws[WS_U_B + i];
    sa += a; sb += b; uab += a * b; uaa += a * a; ubb += b * b;
  }
  for (int i = t; i < NTILES; i += 256) {
    ab += ws[WS_PAB + i]; aa += ws[WS_PAA + i]; bb += ws[WS_PBB + i];
  }
  for (int off = 32; off; off >>= 1) {
    sa  += __shfl_down(sa, off);  sb  += __shfl_down(sb, off);
    uab += __shfl_down(uab, off); uaa += __shfl_down(uaa, off); ubb += __shfl_down(ubb, off);
    ab  += __shfl_down(ab, off);  aa  += __shfl_down(aa, off);  bb  += __shfl_down(bb, off);
  }
  __shared__ double red[4][8];
  int wave = t >> 6, lane = t & 63;
  if (lane == 0) {
    red[wave][0] = sa;  red[wave][1] = sb;  red[wave][2] = uab; red[wave][3] = uaa;
    red[wave][4] = ubb; red[wave][5] = ab;  red[wave][6] = aa;  red[wave][7] = bb;
  }
  __syncthreads();
  if (t == 0) {
    double v[8] = {0,0,0,0,0,0,0,0};
    for (int qq = 0; qq < 4; ++qq) for (int z = 0; z < 8; ++z) v[z] += red[qq][z];
    const double SA = v[0], SB = v[1], UAB = v[2], UAA = v[3], UBB = v[4];
    const double PAB = v[5], PAA = v[6], PBB = v[7];
    const double n = (double)NPTS, nm2 = n - 2.0;
    auto dotv = [&](double P, double U, double sx, double sy) {
      double tX = sx / ((n - 1.0) * nm2), tY = sy / ((n - 1.0) * nm2);
      double RX = sx / nm2, RY = sy / nm2;
      double su  = U / nm2;
      double srr = U / (nm2 * nm2);
      double full = P - 4.0 * su + tY * sx + tX * sy + 2.0 * n * srr + 2.0 * RX * RY
                  - 2.0 * n * tY * RX - 2.0 * n * tX * RY + n * n * tX * tY;
      double dg = n * tX * tY - 2.0 * tX * RY - 2.0 * tY * RX + 4.0 * srr;
      return full - dg;
    };
    const double denomc = n * (n - 3.0);
    double dab = dotv(PAB, UAB, SA, SB) / denomc;
    double daa = dotv(PAA, UAA, SA, SA) / denomc;
    double dbb = dotv(PBB, UBB, SB, SB) / denomc;
    double dn = sqrt(daa * dbb);
    if (dn < 1e-9) dn = 1e-9;
    out[0] = (float)(dab / dn);
  }
}

extern "C" void kernel_launch(void* const* d_in, const int* in_sizes, int n_in,
                              void* d_out, int out_size, void* d_ws, size_t ws_size,
                              hipStream_t stream) {
  const float* fa = (const float*)d_in[0];
  const float* fb = (const float*)d_in[1];
  double* ws = (double*)d_ws;

  _Float16* HA0 = (_Float16*)((char*)d_ws + WS_F16_BYTE_OFF);
  _Float16* HA1 = HA0 + HELEMS;
  _Float16* HB0 = HA1 + HELEMS;
  _Float16* HB1 = HB0 + HELEMS;

  // only the u accumulators need zeroing (P slots + sq are plain stores)
  hipMemsetAsync(d_ws, 0, 8192 * sizeof(double), stream);
  split_kernel<<<dim3(NPTS / 4, 2), 256, 0, stream>>>(fa, fb, HA0, HA1, HB0, HB1, ws);
  gram_kernel<<<NTILES, 256, 0, stream>>>(HA0, HA1, HB0, HB1, ws);
  final_kernel<<<1, 256, 0, stream>>>(ws, (float*)d_out);
}